// Round 11
// baseline (53.207 us; speedup 1.0000x reference)
//
#include <hip/hip_runtime.h>

typedef float    f32x4 __attribute__((ext_vector_type(4)));
typedef _Float16 f16x8 __attribute__((ext_vector_type(8)));
typedef unsigned int u32;
typedef unsigned short u16;

#define B_N   8
#define C_N   128
#define HW_N  4096
#define G_N   16
#define K_N   2048
#define O_N   256
#define BN    64

typedef const __attribute__((address_space(1))) u32 gbl_u32;
typedef __attribute__((address_space(3))) u32 lds_u32;

// ---- prep: W2 f32 [256][2048] -> fp16 fragment-tiled in ws ----
// byte = mtile*65536 + kc*256 + (m&15)*16  (mtile=m>>4, kc=k>>3)
// => per (g,ks): 1 KB contiguous fragment at mtile*65536 + (g*16+ks*4+lk)*256.
__global__ void w2cvt_k(const float* __restrict__ W2, char* __restrict__ w2t) {
  int t = blockIdx.x * 256 + threadIdx.x;   // 65536 threads
  int w = t >> 6, l = t & 63;
  int mtile = w >> 6;                       // 0..15
  int kc    = (w & 63) * 4 + (l >> 4);      // 0..255
  int m     = mtile * 16 + (l & 15);
  const f32x4* src = reinterpret_cast<const f32x4*>(W2 + (size_t)m * K_N + kc * 8);
  f32x4 v0 = src[0], v1 = src[1];
  f16x8 p;
  p[0]=(_Float16)v0[0]; p[1]=(_Float16)v0[1]; p[2]=(_Float16)v0[2]; p[3]=(_Float16)v0[3];
  p[4]=(_Float16)v1[0]; p[5]=(_Float16)v1[1]; p[6]=(_Float16)v1[2]; p[7]=(_Float16)v1[3];
  *reinterpret_cast<f16x8*>(w2t + ((size_t)(mtile * 256 + kc) * 256 + (m & 15) * 16)) = p;
}

// ---- main fused kernel ----
// out[o,p] = b2[o] + sum_g fm[g,p] * sum_c W2[o,g*128+c] * x[c,p]
// Block: 128 o x 64 px, 4 waves, wave tile 32 o x 64 px. fp16 MFMA,
// fm folded into B via packed f16 mul (no P accumulator).
// A streamed via WAVE-PRIVATE async global_load_lds into a per-wave 2-slot
// LDS ring; per-wave counted vmcnt(4); ZERO barriers in the main loop.
__launch_bounds__(256, 3)
__global__ void ccattn_main_k(const float* __restrict__ x,
                              const float* __restrict__ W1,
                              const float* __restrict__ b1,
                              const char* __restrict__ w2t,
                              const float* __restrict__ b2,
                              float* __restrict__ out) {
  __shared__ __align__(16) char Abuf[4][2][4096];  // 32 KB: per-wave 2 slots
  __shared__ u16   xT[BN * C_N];                   // 16 KB
  __shared__ float fmT[G_N][BN];                   // 4 KB

  const int tid = threadIdx.x;
  const int bid = blockIdx.x;
  const int mt  = bid & 1;             // output-channel half
  const int pt  = bid >> 1;            // 512 px-tiles
  const int b   = pt >> 6;             // batch
  const int px0 = (pt & 63) * BN;

  const float* xb = x + (size_t)b * C_N * HW_N + px0;

  // ---- staging: xT (fp16 [px][c], swizzled, b128 writes) + fm (f32) ----
  {
    const int px = tid & 63;
    const int cq = tid >> 6;           // 4 groups each
#pragma unroll
    for (int gg = 0; gg < 4; ++gg) {
      const int g  = cq * 4 + gg;
      const int c0 = g * 8;
      float v[8];
#pragma unroll
      for (int j = 0; j < 8; ++j) v[j] = xb[(size_t)(c0 + j) * HW_N + px];
      float s = b1[g];
#pragma unroll
      for (int j = 0; j < 8; ++j) s += v[j] * W1[g * 8 + j];
      fmT[g][px] = fmaxf(s, 0.0f);
      f16x8 p;
#pragma unroll
      for (int j = 0; j < 8; ++j) p[j] = (_Float16)v[j];
      int byte = (px * 256 + c0 * 2) ^ ((px & 15) << 4);
      *reinterpret_cast<f16x8*>(reinterpret_cast<char*>(xT) + byte) = p;
    }
  }
  __syncthreads();

  // ---- wave decomposition: wave w owns o-rows [w*32, w*32+32) ----
  const int w  = tid >> 6;
  const int l  = tid & 63;
  const int lc = l & 15;
  const int lk = l >> 4;

  char* Ab = (char*)&Abuf[w][0][0];    // wave-private 8 KB ring (2 x 4 KB)
  // A sources: per-lane addresses; half-step h (= g*2 + half) is 2 KB/mtile
  const char* ab0 = w2t + (size_t)(mt * 8 + w * 2 + 0) * 65536 + l * 16;
  const char* ab1 = w2t + (size_t)(mt * 8 + w * 2 + 1) * 65536 + l * 16;

  // stage half-step h into slot h&1: frags {m0kA, m0kB, m1kA, m1kB}
  auto stageH = [&](int h) {
    const char* s0 = ab0 + (size_t)h * 2048;
    const char* s1 = ab1 + (size_t)h * 2048;
    char* d = Ab + (h & 1) * 4096;
    __builtin_amdgcn_global_load_lds((gbl_u32*)s0,          (lds_u32*)(d),        16, 0, 0);
    __builtin_amdgcn_global_load_lds((gbl_u32*)(s0 + 1024), (lds_u32*)(d + 1024), 16, 0, 0);
    __builtin_amdgcn_global_load_lds((gbl_u32*)s1,          (lds_u32*)(d + 2048), 16, 0, 0);
    __builtin_amdgcn_global_load_lds((gbl_u32*)(s1 + 1024), (lds_u32*)(d + 3072), 16, 0, 0);
  };

  stageH(0);
  stageH(1);

  // ---- B-fragment register cache [ks][nf] (valid for every group) ----
  f16x8 bfr[4][4];
#pragma unroll
  for (int ks = 0; ks < 4; ++ks)
#pragma unroll
    for (int nf = 0; nf < 4; ++nf) {
      int px  = nf * 16 + lc;
      int byte = (px * 256 + (ks * 32 + lk * 8) * 2) ^ ((px & 15) << 4);
      bfr[ks][nf] = *reinterpret_cast<const f16x8*>(
          reinterpret_cast<const char*>(xT) + byte);
    }

  f32x4 acc[2][4];
  const f32x4 Z = {0.f, 0.f, 0.f, 0.f};
#pragma unroll
  for (int mf = 0; mf < 2; ++mf)
#pragma unroll
    for (int nf = 0; nf < 4; ++nf) acc[mf][nf] = Z;

  // first rcur: slot 0 (stage(0) landed once <=4 loads outstanding)
  asm volatile("s_waitcnt vmcnt(4)" ::: "memory");
  f16x8 rcur[4], rnext[4];
#pragma unroll
  for (int i = 0; i < 4; ++i)
    rcur[i] = *reinterpret_cast<const f16x8*>(Ab + i * 1024 + l * 16);

  float snC[4], snN[4];
#pragma unroll
  for (int nf = 0; nf < 4; ++nf) {
    snC[nf] = fmT[0][nf * 16 + lc];
    snN[nf] = fmT[1][nf * 16 + lc];
  }

  // ---- main loop: 16 groups x 2 half-steps, wave-private async pipeline ----
#pragma unroll 1
  for (int g = 0; g < 16; ++g) {
    f16x8 s8[4];
#pragma unroll
    for (int nf = 0; nf < 4; ++nf) {
      _Float16 h = (_Float16)snC[nf];
      s8[nf] = (f16x8){h, h, h, h, h, h, h, h};
    }

    // ===== half A: compute (g, ks0/1) from rcur; slot0 recycled =====
    asm volatile("s_waitcnt lgkmcnt(0)" ::: "memory");   // rcur reads done
    { int h = 2 * g + 2; if (h > 31) h = 31; stageH(h); } // overwrite slot0
    __builtin_amdgcn_sched_barrier(0);                    // pin issue order
    asm volatile("s_waitcnt vmcnt(4)" ::: "memory");      // stage(2g+1) landed
#pragma unroll
    for (int i = 0; i < 4; ++i)
      rnext[i] = *reinterpret_cast<const f16x8*>(Ab + 4096 + i * 1024 + l * 16);

    __builtin_amdgcn_s_setprio(1);
#pragma unroll
    for (int nf = 0; nf < 4; ++nf) {
      f16x8 bs = bfr[0][nf] * s8[nf];
      acc[0][nf] = __builtin_amdgcn_mfma_f32_16x16x32_f16(rcur[0], bs, acc[0][nf], 0, 0, 0);
      acc[1][nf] = __builtin_amdgcn_mfma_f32_16x16x32_f16(rcur[2], bs, acc[1][nf], 0, 0, 0);
    }
#pragma unroll
    for (int nf = 0; nf < 4; ++nf) {
      f16x8 bs = bfr[1][nf] * s8[nf];
      acc[0][nf] = __builtin_amdgcn_mfma_f32_16x16x32_f16(rcur[1], bs, acc[0][nf], 0, 0, 0);
      acc[1][nf] = __builtin_amdgcn_mfma_f32_16x16x32_f16(rcur[3], bs, acc[1][nf], 0, 0, 0);
    }
    __builtin_amdgcn_s_setprio(0);

    // ===== half B: compute (g, ks2/3) from rnext; slot1 recycled =====
    asm volatile("s_waitcnt lgkmcnt(0)" ::: "memory");   // rnext reads done
    { int h = 2 * g + 3; if (h > 31) h = 31; stageH(h); } // overwrite slot1
    __builtin_amdgcn_sched_barrier(0);
    asm volatile("s_waitcnt vmcnt(4)" ::: "memory");      // stage(2g+2) landed
#pragma unroll
    for (int i = 0; i < 4; ++i)
      rcur[i] = *reinterpret_cast<const f16x8*>(Ab + i * 1024 + l * 16);

    __builtin_amdgcn_s_setprio(1);
#pragma unroll
    for (int nf = 0; nf < 4; ++nf) {
      f16x8 bs = bfr[2][nf] * s8[nf];
      acc[0][nf] = __builtin_amdgcn_mfma_f32_16x16x32_f16(rnext[0], bs, acc[0][nf], 0, 0, 0);
      acc[1][nf] = __builtin_amdgcn_mfma_f32_16x16x32_f16(rnext[2], bs, acc[1][nf], 0, 0, 0);
    }
#pragma unroll
    for (int nf = 0; nf < 4; ++nf) {
      f16x8 bs = bfr[3][nf] * s8[nf];
      acc[0][nf] = __builtin_amdgcn_mfma_f32_16x16x32_f16(rnext[1], bs, acc[0][nf], 0, 0, 0);
      acc[1][nf] = __builtin_amdgcn_mfma_f32_16x16x32_f16(rnext[3], bs, acc[1][nf], 0, 0, 0);
    }
    __builtin_amdgcn_s_setprio(0);

    // rotate fm lookahead
    const int g2 = (g < 14) ? g + 2 : 15;
#pragma unroll
    for (int nf = 0; nf < 4; ++nf) {
      snC[nf] = snN[nf];
      snN[nf] = fmT[g2][nf * 16 + lc];
    }
  }

  // drain wave-private pipeline before retire
  asm volatile("s_waitcnt vmcnt(0) lgkmcnt(0)" ::: "memory");

  // ---- epilogue: bias + store ----
  float* outb = out + (size_t)b * O_N * HW_N + px0;
#pragma unroll
  for (int mf = 0; mf < 2; ++mf) {
    int o0 = mt * 128 + w * 32 + mf * 16 + lk * 4;
#pragma unroll
    for (int i = 0; i < 4; ++i) {
      float bias = b2[o0 + i];
#pragma unroll
      for (int nf = 0; nf < 4; ++nf) {
        int px = nf * 16 + lc;
        outb[(size_t)(o0 + i) * HW_N + px] = acc[mf][nf][i] + bias;
      }
    }
  }
}

extern "C" void kernel_launch(void* const* d_in, const int* in_sizes, int n_in,
                              void* d_out, int out_size, void* d_ws, size_t ws_size,
                              hipStream_t stream) {
  const float* x  = (const float*)d_in[0];
  const float* W1 = (const float*)d_in[1];
  const float* b1 = (const float*)d_in[2];
  const float* W2 = (const float*)d_in[3];
  const float* b2 = (const float*)d_in[4];
  float* out = (float*)d_out;
  char* w2t = (char*)d_ws;             // 1 MB fragment-tiled fp16 copy of W2

  w2cvt_k<<<256, 256, 0, stream>>>(W2, w2t);
  ccattn_main_k<<<1024, 256, 0, stream>>>(x, W1, b1, w2t, b2, out);
}

// Round 12
// 44.900 us; speedup vs baseline: 1.1850x; 1.1850x over previous
//
#include <hip/hip_runtime.h>

typedef float    f32x4 __attribute__((ext_vector_type(4)));
typedef _Float16 f16x8 __attribute__((ext_vector_type(8)));
typedef unsigned int u32;
typedef unsigned short u16;

#define B_N   8
#define C_N   128
#define HW_N  4096
#define G_N   16
#define K_N   2048
#define O_N   256
#define BN    64

// ---- prep: W2 f32 [256][2048] -> fp16 fragment-tiled in ws ----
// byte = mtile*65536 + (g*16 + ks*4 + lk)*256 + lc*16
// => per (g,ks): 1 KB contiguous fragment; per-lane dwordx4 loads.
__global__ void w2cvt_k(const float* __restrict__ W2, char* __restrict__ w2t) {
  int t = blockIdx.x * 256 + threadIdx.x;   // 65536 threads
  int w = t >> 6, l = t & 63;
  int mtile = w >> 6;                       // 0..15
  int kc    = (w & 63) * 4 + (l >> 4);      // 0..255
  int m     = mtile * 16 + (l & 15);
  const f32x4* src = reinterpret_cast<const f32x4*>(W2 + (size_t)m * K_N + kc * 8);
  f32x4 v0 = src[0], v1 = src[1];
  f16x8 p;
  p[0]=(_Float16)v0[0]; p[1]=(_Float16)v0[1]; p[2]=(_Float16)v0[2]; p[3]=(_Float16)v0[3];
  p[4]=(_Float16)v1[0]; p[5]=(_Float16)v1[1]; p[6]=(_Float16)v1[2]; p[7]=(_Float16)v1[3];
  *reinterpret_cast<f16x8*>(w2t + ((size_t)(mtile * 256 + kc) * 256 + (m & 15) * 16)) = p;
}

// ---- main fused kernel ----
// out[o,p] = b2[o] + sum_g fm[g,p] * sum_c W2[o,g*128+c] * x[c,p]
// Block: 128 o x 64 px, 4 waves, wave tile 32 o x 64 px. fp16 MFMA,
// fm folded into B via packed f16 mul (no P accumulator).
// A-stream: FULL-GROUP register double-buffer (A0/A1), loads for group g+1
// issued BEFORE group g's 32 MFMAs -> prefetch distance ~620 cyc > L2
// latency. Zero barriers, zero LDS traffic for A in the main loop.
__launch_bounds__(256, 2)
__global__ void ccattn_main_k(const float* __restrict__ x,
                              const float* __restrict__ W1,
                              const float* __restrict__ b1,
                              const char* __restrict__ w2t,
                              const float* __restrict__ b2,
                              float* __restrict__ out) {
  __shared__ u16   xT[BN * C_N];       // 16 KB, [px][c] fp16, XOR-swizzled
  __shared__ float fmT[G_N][BN];       // 4 KB

  const int tid = threadIdx.x;
  const int bid = blockIdx.x;
  const int mt  = bid & 1;             // output-channel half
  const int pt  = bid >> 1;            // 512 px-tiles
  const int b   = pt >> 6;             // batch
  const int px0 = (pt & 63) * BN;

  const float* xb = x + (size_t)b * C_N * HW_N + px0;

  // ---- staging: xT (fp16 [px][c], swizzled, b128 writes) + fm (f32) ----
  {
    const int px = tid & 63;
    const int cq = tid >> 6;           // 4 groups each
#pragma unroll
    for (int gg = 0; gg < 4; ++gg) {
      const int g  = cq * 4 + gg;
      const int c0 = g * 8;
      float v[8];
#pragma unroll
      for (int j = 0; j < 8; ++j) v[j] = xb[(size_t)(c0 + j) * HW_N + px];
      float s = b1[g];
#pragma unroll
      for (int j = 0; j < 8; ++j) s += v[j] * W1[g * 8 + j];
      fmT[g][px] = fmaxf(s, 0.0f);
      f16x8 p;
#pragma unroll
      for (int j = 0; j < 8; ++j) p[j] = (_Float16)v[j];
      int byte = (px * 256 + c0 * 2) ^ ((px & 15) << 4);
      *reinterpret_cast<f16x8*>(reinterpret_cast<char*>(xT) + byte) = p;
    }
  }
  __syncthreads();

  // ---- wave decomposition: wave w owns o-rows [w*32, w*32+32) ----
  const int w  = tid >> 6;
  const int l  = tid & 63;
  const int lc = l & 15;
  const int lk = l >> 4;

  // ---- B-fragment register cache [ks][nf] (valid for every group) ----
  f16x8 bfr[4][4];
#pragma unroll
  for (int ks = 0; ks < 4; ++ks)
#pragma unroll
    for (int nf = 0; nf < 4; ++nf) {
      int px  = nf * 16 + lc;
      int byte = (px * 256 + (ks * 32 + lk * 8) * 2) ^ ((px & 15) << 4);
      bfr[ks][nf] = *reinterpret_cast<const f16x8*>(
          reinterpret_cast<const char*>(xT) + byte);
    }

  f32x4 acc[2][4];
  const f32x4 Z = {0.f, 0.f, 0.f, 0.f};
#pragma unroll
  for (int mf = 0; mf < 2; ++mf)
#pragma unroll
    for (int nf = 0; nf < 4; ++nf) acc[mf][nf] = Z;

  // A bases: byte = mtile*65536 + g*4096 + ks*1024 + lk*256 + lc*16
  const char* ab0 = w2t + (size_t)(mt * 8 + w * 2 + 0) * 65536 + lk * 256 + lc * 16;
  const char* ab1 = w2t + (size_t)(mt * 8 + w * 2 + 1) * 65536 + lk * 256 + lc * 16;

  // full-group A buffers: dst[ks] = mtile0, dst[4+ks] = mtile1
  f16x8 A0[8], A1[8];
  float s0[4], s1[4];

#define LDG(dst, g)                                                         \
  {                                                                         \
    _Pragma("unroll")                                                       \
    for (int ks = 0; ks < 4; ++ks) {                                        \
      dst[ks]     = *reinterpret_cast<const f16x8*>(ab0 + (g) * 4096 + ks * 1024); \
      dst[4 + ks] = *reinterpret_cast<const f16x8*>(ab1 + (g) * 4096 + ks * 1024); \
    }                                                                       \
  }
#define LDSN(dst, g)                                                        \
  {                                                                         \
    _Pragma("unroll")                                                       \
    for (int nf = 0; nf < 4; ++nf) dst[nf] = fmT[g][nf * 16 + lc];          \
  }
#define COMP(A, sn)                                                         \
  {                                                                         \
    __builtin_amdgcn_s_setprio(1);                                          \
    _Pragma("unroll")                                                       \
    for (int ks = 0; ks < 4; ++ks) {                                        \
      _Pragma("unroll")                                                     \
      for (int nf = 0; nf < 4; ++nf) {                                      \
        _Float16 h = (_Float16)sn[nf];                                      \
        f16x8 s8 = {h, h, h, h, h, h, h, h};                                \
        f16x8 bs = bfr[ks][nf] * s8;                                        \
        acc[0][nf] = __builtin_amdgcn_mfma_f32_16x16x32_f16(A[ks],     bs, acc[0][nf], 0, 0, 0); \
        acc[1][nf] = __builtin_amdgcn_mfma_f32_16x16x32_f16(A[4 + ks], bs, acc[1][nf], 0, 0, 0); \
      }                                                                     \
    }                                                                       \
    __builtin_amdgcn_s_setprio(0);                                          \
  }

  LDG(A0, 0)
  LDSN(s0, 0)

  // ---- main loop: 16 groups, unroll-2, loads a FULL group ahead ----
#pragma unroll 1
  for (int g = 0; g < 16; g += 2) {
    const int g1 = g + 1;                      // 1..15
    const int g2 = (g + 2 < 16) ? g + 2 : 15;  // clamped dup at tail
    LDG(A1, g1)                                // prefetch group g+1
    LDSN(s1, g1)
    COMP(A0, s0)                               // compute group g
    LDG(A0, g2)                                // prefetch group g+2
    LDSN(s0, g2)
    COMP(A1, s1)                               // compute group g+1
  }
#undef LDG
#undef LDSN
#undef COMP

  // ---- epilogue: bias + store ----
  float* outb = out + (size_t)b * O_N * HW_N + px0;
#pragma unroll
  for (int mf = 0; mf < 2; ++mf) {
    int o0 = mt * 128 + w * 32 + mf * 16 + lk * 4;
#pragma unroll
    for (int i = 0; i < 4; ++i) {
      float bias = b2[o0 + i];
#pragma unroll
      for (int nf = 0; nf < 4; ++nf) {
        int px = nf * 16 + lc;
        outb[(size_t)(o0 + i) * HW_N + px] = acc[mf][nf][i] + bias;
      }
    }
  }
}

extern "C" void kernel_launch(void* const* d_in, const int* in_sizes, int n_in,
                              void* d_out, int out_size, void* d_ws, size_t ws_size,
                              hipStream_t stream) {
  const float* x  = (const float*)d_in[0];
  const float* W1 = (const float*)d_in[1];
  const float* b1 = (const float*)d_in[2];
  const float* W2 = (const float*)d_in[3];
  const float* b2 = (const float*)d_in[4];
  float* out = (float*)d_out;
  char* w2t = (char*)d_ws;             // 1 MB fragment-tiled fp16 copy of W2

  w2cvt_k<<<256, 256, 0, stream>>>(W2, w2t);
  ccattn_main_k<<<1024, 256, 0, stream>>>(x, W1, b1, w2t, b2, out);
}

// Round 13
// 41.082 us; speedup vs baseline: 1.2951x; 1.0929x over previous
//
#include <hip/hip_runtime.h>

typedef float    f32x4 __attribute__((ext_vector_type(4)));
typedef _Float16 f16x8 __attribute__((ext_vector_type(8)));
typedef unsigned int u32;
typedef unsigned short u16;

#define B_N   8
#define C_N   128
#define HW_N  4096
#define G_N   16
#define K_N   2048
#define O_N   256
#define BN    128

// ---- prep: W2 f32 [256][2048] -> fp16 fragment-tiled in ws ----
// byte = mtile*65536 + (g*16 + ks*4 + lk)*256 + lc*16
// => per (g,ks): 1 KB contiguous fragment; per-lane dwordx4 loads.
__global__ void w2cvt_k(const float* __restrict__ W2, char* __restrict__ w2t) {
  int t = blockIdx.x * 256 + threadIdx.x;   // 65536 threads
  int w = t >> 6, l = t & 63;
  int mtile = w >> 6;                       // 0..15
  int kc    = (w & 63) * 4 + (l >> 4);      // 0..255
  int m     = mtile * 16 + (l & 15);
  const f32x4* src = reinterpret_cast<const f32x4*>(W2 + (size_t)m * K_N + kc * 8);
  f32x4 v0 = src[0], v1 = src[1];
  f16x8 p;
  p[0]=(_Float16)v0[0]; p[1]=(_Float16)v0[1]; p[2]=(_Float16)v0[2]; p[3]=(_Float16)v0[3];
  p[4]=(_Float16)v1[0]; p[5]=(_Float16)v1[1]; p[6]=(_Float16)v1[2]; p[7]=(_Float16)v1[3];
  *reinterpret_cast<f16x8*>(w2t + ((size_t)(mtile * 256 + kc) * 256 + (m & 15) * 16)) = p;
}

// ---- main fused kernel ----
// out[o,p] = b2[o] + sum_g fm[g,p] * sum_c W2[o,g*128+c] * x[c,p]
// Block: 128 o x 128 px, 4 waves (2 wm x 2 wn), wave tile 64o x 64px.
// fp16 MFMA, fm folded into B (packed f16 mul, no P accumulator).
// BN=128 halves L2 A-traffic vs BN=64 (1 MB x 32768/BN total); A-stream
// explicitly double-buffered in registers at half-group granularity
// (distance = 32 MFMA). Zero barriers in the main loop; 2 blocks/CU.
__launch_bounds__(256, 2)
__global__ void ccattn_main_k(const float* __restrict__ x,
                              const float* __restrict__ W1,
                              const float* __restrict__ b1,
                              const char* __restrict__ w2t,
                              const float* __restrict__ b2,
                              float* __restrict__ out) {
  __shared__ u16   xT[BN * C_N];       // 32 KB, [px][c] fp16, XOR-swizzled
  __shared__ float fmT[G_N][BN];       // 8 KB

  const int tid = threadIdx.x;
  const int bid = blockIdx.x;
  const int mt  = bid >> 8;            // pt-major: co-resident blocks share mt
  const int pt  = bid & 255;
  const int b   = pt >> 5;
  const int px0 = (pt & 31) * BN;

  const float* xb = x + (size_t)b * C_N * HW_N + px0;

  // ---- staging: xT (fp16 [px][c], swizzled, b128 writes) + fm (f32) ----
  {
    const int px    = tid & 127;
    const int chalf = tid >> 7;        // channels [0,64) or [64,128)
#pragma unroll
    for (int gg = 0; gg < 8; ++gg) {
      const int g  = chalf * 8 + gg;
      const int c0 = g * 8;
      float v[8];
#pragma unroll
      for (int j = 0; j < 8; ++j) v[j] = xb[(size_t)(c0 + j) * HW_N + px];
      float s = b1[g];
#pragma unroll
      for (int j = 0; j < 8; ++j) s += v[j] * W1[g * 8 + j];
      fmT[g][px] = fmaxf(s, 0.0f);
      f16x8 p;
#pragma unroll
      for (int j = 0; j < 8; ++j) p[j] = (_Float16)v[j];
      int byte = (px * 256 + c0 * 2) ^ ((px & 15) << 4);
      *reinterpret_cast<f16x8*>(reinterpret_cast<char*>(xT) + byte) = p;
    }
  }
  __syncthreads();

  // ---- wave decomposition ----
  const int w  = tid >> 6;
  const int l  = tid & 63;
  const int wm = w & 1;                // o offset 0/64
  const int wn = w >> 1;               // px offset 0/64
  const int lc = l & 15;
  const int lk = l >> 4;

  // ---- B-fragment register cache [ks][nf] (valid for every group) ----
  f16x8 bfr[4][4];
#pragma unroll
  for (int ks = 0; ks < 4; ++ks)
#pragma unroll
    for (int nf = 0; nf < 4; ++nf) {
      int px  = wn * 64 + nf * 16 + lc;
      int byte = (px * 256 + (ks * 32 + lk * 8) * 2) ^ ((px & 15) << 4);
      bfr[ks][nf] = *reinterpret_cast<const f16x8*>(
          reinterpret_cast<const char*>(xT) + byte);
    }

  f32x4 acc[4][4];
  const f32x4 Z = {0.f, 0.f, 0.f, 0.f};
#pragma unroll
  for (int mf = 0; mf < 4; ++mf)
#pragma unroll
    for (int nf = 0; nf < 4; ++nf) acc[mf][nf] = Z;

  // A base: byte = mtile*65536 + g*4096 + ks*1024 + lk*256 + lc*16,
  // mtile = mt*8 + wm*4 + mf
  const char* abm = w2t + (size_t)(mt * 8 + wm * 4) * 65536 + lk * 256 + lc * 16;

  // half-group A buffers: buf[mf*2 + ks2] for ks = half*2 + ks2
  f16x8 pA[8], pB[8];

#define LDH(dst, g, half)                                                   \
  {                                                                         \
    _Pragma("unroll")                                                       \
    for (int mf = 0; mf < 4; ++mf) {                                        \
      _Pragma("unroll")                                                     \
      for (int ks2 = 0; ks2 < 2; ++ks2)                                     \
        dst[mf * 2 + ks2] = *reinterpret_cast<const f16x8*>(                \
            abm + mf * 65536 + (g) * 4096 + ((half) * 2 + ks2) * 1024);     \
    }                                                                       \
  }
#define COMP(buf, sn, half)                                                 \
  {                                                                         \
    __builtin_amdgcn_s_setprio(1);                                          \
    _Pragma("unroll")                                                       \
    for (int ks2 = 0; ks2 < 2; ++ks2) {                                     \
      _Pragma("unroll")                                                     \
      for (int nf = 0; nf < 4; ++nf) {                                      \
        _Float16 h = (_Float16)sn[nf];                                      \
        f16x8 s8 = {h, h, h, h, h, h, h, h};                                \
        f16x8 bs = bfr[(half) * 2 + ks2][nf] * s8;                          \
        _Pragma("unroll")                                                   \
        for (int mf = 0; mf < 4; ++mf)                                      \
          acc[mf][nf] = __builtin_amdgcn_mfma_f32_16x16x32_f16(             \
              buf[mf * 2 + ks2], bs, acc[mf][nf], 0, 0, 0);                 \
      }                                                                     \
    }                                                                       \
    __builtin_amdgcn_s_setprio(0);                                          \
  }

  LDH(pA, 0, 0)
  LDH(pB, 0, 1)

  float snC[4], snN[4];
#pragma unroll
  for (int nf = 0; nf < 4; ++nf) {
    snC[nf] = fmT[0][wn * 64 + nf * 16 + lc];
    snN[nf] = fmT[1][wn * 64 + nf * 16 + lc];
  }

  // ---- main loop: 16 groups, half-group reg-dbuf, no barriers ----
#pragma unroll 1
  for (int g = 0; g < 16; ++g) {
    const int gn = (g < 15) ? g + 1 : 15;   // clamped dup at tail (harmless)
    COMP(pA, snC, 0)                        // compute half0 of g
    LDH(pA, gn, 0)                          // prefetch half0 of g+1 (dist 32 MFMA)
    COMP(pB, snC, 1)                        // compute half1 of g
    LDH(pB, gn, 1)                          // prefetch half1 of g+1
    const int g2 = (g < 14) ? g + 2 : 15;
#pragma unroll
    for (int nf = 0; nf < 4; ++nf) {
      snC[nf] = snN[nf];
      snN[nf] = fmT[g2][wn * 64 + nf * 16 + lc];
    }
  }
#undef LDH
#undef COMP

  // ---- epilogue: bias + store ----
  float* outb = out + (size_t)b * O_N * HW_N + px0;
#pragma unroll
  for (int mf = 0; mf < 4; ++mf) {
    int o0 = mt * 128 + wm * 64 + mf * 16 + lk * 4;
#pragma unroll
    for (int i = 0; i < 4; ++i) {
      float bias = b2[o0 + i];
#pragma unroll
      for (int nf = 0; nf < 4; ++nf) {
        int px = wn * 64 + nf * 16 + lc;
        outb[(size_t)(o0 + i) * HW_N + px] = acc[mf][nf][i] + bias;
      }
    }
  }
}

extern "C" void kernel_launch(void* const* d_in, const int* in_sizes, int n_in,
                              void* d_out, int out_size, void* d_ws, size_t ws_size,
                              hipStream_t stream) {
  const float* x  = (const float*)d_in[0];
  const float* W1 = (const float*)d_in[1];
  const float* b1 = (const float*)d_in[2];
  const float* W2 = (const float*)d_in[3];
  const float* b2 = (const float*)d_in[4];
  float* out = (float*)d_out;
  char* w2t = (char*)d_ws;             // 1 MB fragment-tiled fp16 copy of W2

  w2cvt_k<<<256, 256, 0, stream>>>(W2, w2t);
  ccattn_main_k<<<512, 256, 0, stream>>>(x, W1, b1, w2t, b2, out);
}

// Round 14
// 40.195 us; speedup vs baseline: 1.3237x; 1.0221x over previous
//
#include <hip/hip_runtime.h>

typedef float f32x4 __attribute__((ext_vector_type(4)));
typedef int   i32x4 __attribute__((ext_vector_type(4)));
typedef unsigned int u32;

#define HW_N  4096
#define C_N   128
#define G_N   16
#define K_N   2048
#define O_N   256
#define BN    128

__device__ __forceinline__ u32 pack4(float a, float b, float c, float d, float inv) {
  int q0 = (int)rintf(a * inv), q1 = (int)rintf(b * inv);
  int q2 = (int)rintf(c * inv), q3 = (int)rintf(d * inv);
  return (u32)(q0 & 255) | ((u32)(q1 & 255) << 8) |
         ((u32)(q2 & 255) << 16) | ((u32)(q3 & 255) << 24);
}

// ---- prep: W2 f32 [256][2048] -> i8 fragment-tiled + per-row scale sw ----
// frag id = mtile*32 + g*2 + ks2 (16x64 i8 tile); lane l holds
// row = mtile*16 + (l&15), k = g*128 + ks2*64 + (l>>4)*16 + j, 16 B per lane.
// One wave per W2 row: absmax-reduce, quantize, scatter two 16B chunks.
__global__ void w2q_k(const float* __restrict__ W2, char* __restrict__ w2q,
                      float* __restrict__ sw) {
  int o = (blockIdx.x * 256 + threadIdx.x) >> 6;   // 0..255
  int l = threadIdx.x & 63;
  const f32x4* rp = reinterpret_cast<const f32x4*>(W2 + (size_t)o * K_N + l * 32);
  float v[32]; float am = 0.f;
#pragma unroll
  for (int q = 0; q < 8; ++q) {
    f32x4 t = rp[q];
#pragma unroll
    for (int j = 0; j < 4; ++j) { v[q * 4 + j] = t[j]; am = fmaxf(am, fabsf(t[j])); }
  }
#pragma unroll
  for (int s = 1; s < 64; s <<= 1) am = fmaxf(am, __shfl_xor(am, s, 64));
  am = fmaxf(am, 1e-30f);
  float inv = 127.0f / am;
  if (l == 0) sw[o] = am / 127.0f;
#pragma unroll
  for (int c = 0; c < 2; ++c) {
    int k0 = l * 32 + c * 16;
    u32 pk[4];
#pragma unroll
    for (int q = 0; q < 4; ++q)
      pk[q] = pack4(v[c * 16 + q * 4 + 0], v[c * 16 + q * 4 + 1],
                    v[c * 16 + q * 4 + 2], v[c * 16 + q * 4 + 3], inv);
    int frag = (o >> 4) * 32 + (k0 >> 7) * 2 + ((k0 >> 6) & 1);
    int lif  = (o & 15) + ((k0 >> 4) & 3) * 16;
    *reinterpret_cast<i32x4*>(w2q + (size_t)frag * 1024 + lif * 16) =
        *reinterpret_cast<i32x4*>(pk);
  }
}

// ---- main fused kernel ----
// out[o,p] = b2[o] + sw[o]*sx[p] * sum_g fm[g,p] * P_g[o,p],
// P_g = i8-dot of qw (group g cols) and qx  (exact i32 accumulate).
// Block: 128 o x 128 px, 4 waves (2 wm x 2 wn), wave tile 64o x 64px.
// i8 MFMA 16x16x64 (2x f16 rate, half the A bytes). qx invariant across
// groups -> B fragments cached in regs. Zero barriers in the main loop.
__launch_bounds__(256, 2)
__global__ void ccattn_main_k(const float* __restrict__ x,
                              const float* __restrict__ W1,
                              const float* __restrict__ b1,
                              const char* __restrict__ w2q,
                              const float* __restrict__ sw,
                              const float* __restrict__ b2,
                              float* __restrict__ out) {
  __shared__ char  qxT[BN * 128];      // 16 KB, [px][c] i8, granule-swizzled
  __shared__ float fmT[G_N][BN];       // 8 KB
  __shared__ float sxT[BN];
  __shared__ float lmax[2][BN];

  const int tid = threadIdx.x;
  const int bid = blockIdx.x;
  const int mt  = bid >> 8;            // pt-major: co-resident blocks share mt
  const int pt  = bid & 255;
  const int b   = pt >> 5;
  const int px0 = (pt & 31) * BN;

  const float* xb = x + (size_t)b * C_N * HW_N + px0;

  // ---- staging pass A: read x (exact f32), fm, per-half absmax ----
  const int px    = tid & 127;
  const int chalf = tid >> 7;          // channels [0,64) or [64,128)
  float v[8][8];
  {
    float am = 0.f;
#pragma unroll
    for (int gg = 0; gg < 8; ++gg) {
      const int g  = chalf * 8 + gg;
      const int c0 = g * 8;
      float s = b1[g];
#pragma unroll
      for (int j = 0; j < 8; ++j) {
        float t = xb[(size_t)(c0 + j) * HW_N + px];
        v[gg][j] = t;
        s += t * W1[g * 8 + j];
        am = fmaxf(am, fabsf(t));
      }
      fmT[g][px] = fmaxf(s, 0.0f);
    }
    lmax[chalf][px] = am;
  }
  __syncthreads();

  // ---- staging pass B: per-pixel scale + quantize to qxT ----
  {
    float amax = fmaxf(fmaxf(lmax[0][px], lmax[1][px]), 1e-30f);
    float inv  = 127.0f / amax;
    if (!chalf) sxT[px] = amax / 127.0f;
#pragma unroll
    for (int gr = 0; gr < 4; ++gr) {   // 4 granules of 16 channels each
      u32 pk[4];
#pragma unroll
      for (int q = 0; q < 4; ++q) {
        const int gg = gr * 2 + (q >> 1);
        const int j0 = (q & 1) * 4;
        pk[q] = pack4(v[gg][j0], v[gg][j0 + 1], v[gg][j0 + 2], v[gg][j0 + 3], inv);
      }
      int gidx = chalf * 4 + gr;
      int byte = px * 128 + ((gidx ^ (px & 7)) << 4);
      *reinterpret_cast<i32x4*>(qxT + byte) = *reinterpret_cast<i32x4*>(pk);
    }
  }
  __syncthreads();

  // ---- wave decomposition ----
  const int w  = tid >> 6;
  const int l  = tid & 63;
  const int wm = w & 1;                // o offset 0/64
  const int wn = w >> 1;               // px offset 0/64
  const int lc = l & 15;
  const int lk = l >> 4;

  // ---- B-fragment register cache [ks2][nf] (group-invariant!) ----
  i32x4 bfr[2][4];
#pragma unroll
  for (int ks2 = 0; ks2 < 2; ++ks2)
#pragma unroll
    for (int nf = 0; nf < 4; ++nf) {
      int p    = wn * 64 + nf * 16 + lc;
      int gidx = ks2 * 4 + lk;
      int byte = p * 128 + ((gidx ^ (p & 7)) << 4);
      bfr[ks2][nf] = *reinterpret_cast<const i32x4*>(qxT + byte);
    }

  f32x4 acc[4][4];
  const f32x4 Z = {0.f, 0.f, 0.f, 0.f};
#pragma unroll
  for (int mf = 0; mf < 4; ++mf)
#pragma unroll
    for (int nf = 0; nf < 4; ++nf) acc[mf][nf] = Z;

  // A base: frag byte = mtile*32768 + g*2048 + ks2*1024 + l*16
  const char* abm = w2q + (size_t)(mt * 8 + wm * 4) * 32768 + l * 16;

  i32x4 A0[8], A1[8];
  float snC[4], snN[4];

#define LDG(dst, g)                                                          \
  {                                                                          \
    _Pragma("unroll")                                                        \
    for (int mf = 0; mf < 4; ++mf) {                                         \
      dst[mf * 2]     = *reinterpret_cast<const i32x4*>(abm + (size_t)mf * 32768 + (g) * 2048);        \
      dst[mf * 2 + 1] = *reinterpret_cast<const i32x4*>(abm + (size_t)mf * 32768 + (g) * 2048 + 1024); \
    }                                                                        \
  }
#define LDSN(dst, g)                                                         \
  {                                                                          \
    _Pragma("unroll")                                                        \
    for (int nf = 0; nf < 4; ++nf) dst[nf] = fmT[g][wn * 64 + nf * 16 + lc]; \
  }
#define COMP(buf, sn)                                                        \
  {                                                                          \
    __builtin_amdgcn_s_setprio(1);                                           \
    _Pragma("unroll")                                                        \
    for (int nf = 0; nf < 4; ++nf) {                                         \
      i32x4 P[4];                                                            \
      _Pragma("unroll")                                                      \
      for (int mf = 0; mf < 4; ++mf)                                         \
        P[mf] = __builtin_amdgcn_mfma_i32_16x16x64_i8(                       \
            buf[mf * 2], bfr[0][nf], (i32x4){0, 0, 0, 0}, 0, 0, 0);          \
      _Pragma("unroll")                                                      \
      for (int mf = 0; mf < 4; ++mf)                                         \
        P[mf] = __builtin_amdgcn_mfma_i32_16x16x64_i8(                       \
            buf[mf * 2 + 1], bfr[1][nf], P[mf], 0, 0, 0);                    \
      _Pragma("unroll")                                                      \
      for (int mf = 0; mf < 4; ++mf) {                                       \
        _Pragma("unroll")                                                    \
        for (int i = 0; i < 4; ++i)                                          \
          acc[mf][nf][i] += sn[nf] * (float)P[mf][i];                        \
      }                                                                      \
    }                                                                        \
    __builtin_amdgcn_s_setprio(0);                                           \
  }

  LDG(A0, 0)
  LDSN(snC, 0)

  // ---- main loop: 16 groups, unroll-2, full-group reg-dbuf, no barriers ----
#pragma unroll 1
  for (int g = 0; g < 16; g += 2) {
    LDG(A1, g + 1)
    LDSN(snN, g + 1)
    COMP(A0, snC)
    const int g2 = (g + 2 < 16) ? g + 2 : 15;   // clamped dup load (harmless)
    LDG(A0, g2)
    LDSN(snC, g2)
    COMP(A1, snN)
  }
#undef LDG
#undef LDSN
#undef COMP

  // ---- epilogue: out = acc*sw[o]*sx[p] + b2[o] ----
  float sxv[4];
#pragma unroll
  for (int nf = 0; nf < 4; ++nf) sxv[nf] = sxT[wn * 64 + nf * 16 + lc];
  float* outb = out + (size_t)b * O_N * HW_N + px0;
#pragma unroll
  for (int mf = 0; mf < 4; ++mf) {
    int o0 = mt * 128 + wm * 64 + mf * 16 + lk * 4;
#pragma unroll
    for (int i = 0; i < 4; ++i) {
      float so   = sw[o0 + i];
      float bias = b2[o0 + i];
#pragma unroll
      for (int nf = 0; nf < 4; ++nf) {
        int p = wn * 64 + nf * 16 + lc;
        outb[(size_t)(o0 + i) * HW_N + p] = acc[mf][nf][i] * so * sxv[nf] + bias;
      }
    }
  }
}

extern "C" void kernel_launch(void* const* d_in, const int* in_sizes, int n_in,
                              void* d_out, int out_size, void* d_ws, size_t ws_size,
                              hipStream_t stream) {
  const float* x  = (const float*)d_in[0];
  const float* W1 = (const float*)d_in[1];
  const float* b1 = (const float*)d_in[2];
  const float* W2 = (const float*)d_in[3];
  const float* b2 = (const float*)d_in[4];
  float* out = (float*)d_out;
  char*  w2q = (char*)d_ws;                       // 512 KB i8 tiled W2
  float* sw  = (float*)((char*)d_ws + 524288);    // 256 f32 row scales

  w2q_k<<<64, 256, 0, stream>>>(W2, w2q, sw);
  ccattn_main_k<<<512, 256, 0, stream>>>(x, W1, b1, w2q, sw, b2, out);
}